// Round 7
// baseline (243.554 us; speedup 1.0000x reference)
//
#include <hip/hip_runtime.h>
#include <hip/hip_bf16.h>
#include <math.h>

// NoisyTopkRouter round 7: wave-autonomous K-loop — ZERO LDS / ZERO barriers
// in the main loop, so no vmcnt(0) drains and register prefetch is real.
// - Each wave: 32 tokens x 64 cols (route ntiles 2wc,2wc+1 + noise +4).
//   A-frag (A[m=lane&15][k=quad*8+j]) == 8 consecutive row-major floats per
//   lane -> each lane converts its own loaded data. 24 MFMAs/chunk.
// - Raw-A register pipeline holds chunks kc+1..kc+3 (convert slack = 2 full
//   iterations > HBM latency). B prefetched 1 iteration ahead (L1/L2-hot).
// - Epilogue (only LDS use): Cs[token][expert], 2 barriers, top-2, scatter.

#define T_TOKENS 32768
#define D_MODEL  1024
#define NE       64
#define NCOL     128
#define M_TILE   64
#define NCHUNK   32
#define CS_LD    68
#define OUT_IDX_BASE ((size_t)T_TOKENS * NE)
#define W_ELEMS  (NCOL * D_MODEL)

typedef short  bf16x8  __attribute__((ext_vector_type(8)));
typedef float  floatx4 __attribute__((ext_vector_type(4)));

__device__ __forceinline__ float softplus_f(float x) {
    return fmaxf(x, 0.f) + log1pf(expf(-fabsf(x)));
}

// 8 floats -> bf16 hi/lo frags (RNE hi, exact residual, RNE lo) — numerics
// identical to rounds 2-6 (all passed).
__device__ __forceinline__ void cvt8frag(const float4 a, const float4 b,
                                         bf16x8* hi, bf16x8* lo) {
    float v[8] = {a.x, a.y, a.z, a.w, b.x, b.y, b.z, b.w};
    int hw[4], lw[4];
    #pragma unroll
    for (int p = 0; p < 4; ++p) {
        float2 f2 = make_float2(v[2 * p], v[2 * p + 1]);
        __hip_bfloat162 h2 = __float22bfloat162_rn(f2);
        int u; __builtin_memcpy(&u, &h2, 4);
        float h0 = __uint_as_float(((unsigned)u) << 16);
        float h1 = __uint_as_float(((unsigned)u) & 0xFFFF0000u);
        float2 l2 = make_float2(v[2 * p] - h0, v[2 * p + 1] - h1);
        __hip_bfloat162 L2 = __float22bfloat162_rn(l2);
        int ul; __builtin_memcpy(&ul, &L2, 4);
        hw[p] = u; lw[p] = ul;
    }
    int4 hp = make_int4(hw[0], hw[1], hw[2], hw[3]);
    int4 lp = make_int4(lw[0], lw[1], lw[2], lw[3]);
    __builtin_memcpy(hi, &hp, 16);
    __builtin_memcpy(lo, &lp, 16);
}

// ---------------- prepack: W -> hi/lo bf16 in B-frag order ----------------
// elem = ((ntile*128 + kgrp)*16 + n16)*8 + j ; value = W[ntile*16+n16][kgrp*8+j]
__global__ __launch_bounds__(256) void prepack_w(
    const float* __restrict__ Wr, const float* __restrict__ Wn,
    short* __restrict__ Bh, short* __restrict__ Bl)
{
    int g   = blockIdx.x * 256 + threadIdx.x;
    int n   = g & 15;
    int kg  = (g >> 4) & 127;
    int t2  = g >> 11;
    int col = t2 * 16 + n;
    const float* src = (col < NE ? Wr + (size_t)col * D_MODEL
                                 : Wn + (size_t)(col - NE) * D_MODEL) + kg * 8;
    float4 a = *(const float4*)src;
    float4 b = *(const float4*)(src + 4);
    bf16x8 hi, lo;
    cvt8frag(a, b, &hi, &lo);
    *(bf16x8*)(Bh + (size_t)g * 8) = hi;
    *(bf16x8*)(Bl + (size_t)g * 8) = lo;
}

// ---------------- main fused kernel ----------------
__global__ __launch_bounds__(256) void router_mfma(
    const float* __restrict__ A,
    const float* __restrict__ noise,
    const float* __restrict__ br,
    const float* __restrict__ bn,
    const short* __restrict__ Bh,
    const short* __restrict__ Bl,
    float* __restrict__ out)
{
    __shared__ float Cs[M_TILE * CS_LD];
    __shared__ float s_p1[M_TILE], s_p2[M_TILE];
    __shared__ int   s_e1[M_TILE], s_e2[M_TILE];

    const int tid  = threadIdx.x;
    const int lane = tid & 63;
    const int wid  = tid >> 6;
    const int th   = wid >> 1;   // token half: tokens th*32 .. +31
    const int wc   = wid & 1;    // col half: route cols wc*32 .. +31
    const int n16  = lane & 15;
    const int quad = lane >> 4;
    const int m0   = blockIdx.x * M_TILE;

    // A row pointers for the wave's two m-frags
    const float* pA0 = A + (size_t)(m0 + th * 32 + n16) * D_MODEL + quad * 8;
    const float* pA1 = pA0 + (size_t)16 * D_MODEL;

    // B frag bases: f=0,1 route ntiles wc*2+f ; f=2,3 noise ntiles 4+wc*2+(f-2)
    int bBase[4];
    #pragma unroll
    for (int f = 0; f < 4; ++f) {
        int ntile = (f < 2) ? (wc * 2 + f) : (4 + wc * 2 + (f - 2));
        bBase[f] = ((ntile * 128 + quad) * 16 + n16) * 8;
    }

    floatx4 acc[2][4];   // [m-frag][f]
    #pragma unroll
    for (int mf = 0; mf < 2; ++mf)
        #pragma unroll
        for (int f = 0; f < 4; ++f) acc[mf][f] = (floatx4)0.f;

    // ---- prologue: raw chunks 0,1,2; convert chunk 0; B(0) ----
    float4 r1[2][2], r2[2][2];
    bf16x8 ah[2], al[2];
    {
        float4 r0a0 = *(const float4*)(pA0);
        float4 r0a1 = *(const float4*)(pA0 + 4);
        float4 r0b0 = *(const float4*)(pA1);
        float4 r0b1 = *(const float4*)(pA1 + 4);
        r1[0][0] = *(const float4*)(pA0 + 32);  r1[0][1] = *(const float4*)(pA0 + 36);
        r1[1][0] = *(const float4*)(pA1 + 32);  r1[1][1] = *(const float4*)(pA1 + 36);
        r2[0][0] = *(const float4*)(pA0 + 64);  r2[0][1] = *(const float4*)(pA0 + 68);
        r2[1][0] = *(const float4*)(pA1 + 64);  r2[1][1] = *(const float4*)(pA1 + 68);
        cvt8frag(r0a0, r0a1, &ah[0], &al[0]);
        cvt8frag(r0b0, r0b1, &ah[1], &al[1]);
    }
    bf16x8 bhc[4], blc[4];
    #pragma unroll
    for (int f = 0; f < 4; ++f) {
        bhc[f] = *(const bf16x8*)(Bh + bBase[f]);
        blc[f] = *(const bf16x8*)(Bl + bBase[f]);
    }

    for (int kc = 0; kc < NCHUNK; ++kc) {
        // raw A for chunk kc+3 (deepest slack: consumed 2 iterations later)
        float4 r3[2][2];
        if (kc + 3 < NCHUNK) {
            const int o = (kc + 3) * 32;
            r3[0][0] = *(const float4*)(pA0 + o);  r3[0][1] = *(const float4*)(pA0 + o + 4);
            r3[1][0] = *(const float4*)(pA1 + o);  r3[1][1] = *(const float4*)(pA1 + o + 4);
        }
        // B for chunk kc+1 (1 iteration of slack; L1/L2-hot)
        bf16x8 bhn[4], bln[4];
        if (kc + 1 < NCHUNK) {
            const int o = (kc + 1) * 512;
            #pragma unroll
            for (int f = 0; f < 4; ++f) {
                bhn[f] = *(const bf16x8*)(Bh + bBase[f] + o);
                bln[f] = *(const bf16x8*)(Bl + bBase[f] + o);
            }
        }

        // 24 MFMAs on chunk kc (ah/al and bhc/blc are ready — loaded/converted
        // at least one full iteration ago). 8 independent chains, depth 3.
        #pragma unroll
        for (int mf = 0; mf < 2; ++mf)
            #pragma unroll
            for (int f = 0; f < 4; ++f) {
                acc[mf][f] = __builtin_amdgcn_mfma_f32_16x16x32_bf16(ah[mf], bhc[f], acc[mf][f], 0, 0, 0);
                acc[mf][f] = __builtin_amdgcn_mfma_f32_16x16x32_bf16(ah[mf], blc[f], acc[mf][f], 0, 0, 0);
                acc[mf][f] = __builtin_amdgcn_mfma_f32_16x16x32_bf16(al[mf], bhc[f], acc[mf][f], 0, 0, 0);
            }

        // convert chunk kc+1 (raw loaded 2 iterations ago) into ah/al
        if (kc + 1 < NCHUNK) {
            cvt8frag(r1[0][0], r1[0][1], &ah[0], &al[0]);
            cvt8frag(r1[1][0], r1[1][1], &ah[1], &al[1]);
        }

        // rotate pipelines
        #pragma unroll
        for (int mf = 0; mf < 2; ++mf) {
            r1[mf][0] = r2[mf][0]; r1[mf][1] = r2[mf][1];
            r2[mf][0] = r3[mf][0]; r2[mf][1] = r3[mf][1];
        }
        #pragma unroll
        for (int f = 0; f < 4; ++f) { bhc[f] = bhn[f]; blc[f] = bln[f]; }
    }

    // ---- lane-local fuse: noisy = route + noise * softplus(noise_logit) ----
    // D layout: col = lane&15, row = quad*4 + r
    #pragma unroll
    for (int fi = 0; fi < 2; ++fi) {
        int e = wc * 32 + fi * 16 + n16;
        float brv = br[e], bnv = bn[e];
        #pragma unroll
        for (int mf = 0; mf < 2; ++mf)
            #pragma unroll
            for (int rr = 0; rr < 4; ++rr) {
                int t = th * 32 + mf * 16 + quad * 4 + rr;
                float nz    = noise[(size_t)(m0 + t) * NE + e];
                float route = acc[mf][fi]     [rr] + brv;
                float nl    = acc[mf][fi + 2] [rr] + bnv;
                Cs[t * CS_LD + e] = fmaf(nz, softplus_f(nl), route);
            }
    }
    __syncthreads();

    // ---- top-2 + softmax (one thread per token; in-order scan = stable ties) ----
    if (tid < M_TILE) {
        const int t = tid;
        float v1 = -INFINITY, v2 = -INFINITY;
        int e1 = 0, e2 = 0;
        #pragma unroll
        for (int e4 = 0; e4 < 16; ++e4) {
            float4 q = *(const float4*)&Cs[t * CS_LD + e4 * 4];
            float qa[4] = {q.x, q.y, q.z, q.w};
            #pragma unroll
            for (int c = 0; c < 4; ++c) {
                float v = qa[c];
                int e = e4 * 4 + c;
                if (v > v1) { v2 = v1; e2 = e1; v1 = v; e1 = e; }
                else if (v > v2) { v2 = v; e2 = e; }
            }
        }
        float ex = expf(v2 - v1);
        float denom = 1.f + ex;
        s_p1[t] = 1.f / denom;
        s_p2[t] = ex / denom;
        s_e1[t] = e1;
        s_e2[t] = e2;
        float2 iv = make_float2((float)e1, (float)e2);
        *(float2*)(out + OUT_IDX_BASE + (size_t)(m0 + t) * 2) = iv;
    }
    __syncthreads();

    // ---- coalesced scatter of router_output [64 tokens x 64 experts] ----
    #pragma unroll
    for (int i = 0; i < 4; ++i) {
        int gi = i * 256 + tid;       // 0..1023 float4s
        int t  = gi >> 4;
        int e0 = (gi & 15) * 4;
        float p1 = s_p1[t], p2 = s_p2[t];
        int   e1 = s_e1[t], e2 = s_e2[t];
        float4 v;
        v.x = (e0 + 0 == e1) ? p1 : ((e0 + 0 == e2) ? p2 : 0.f);
        v.y = (e0 + 1 == e1) ? p1 : ((e0 + 1 == e2) ? p2 : 0.f);
        v.z = (e0 + 2 == e1) ? p1 : ((e0 + 2 == e2) ? p2 : 0.f);
        v.w = (e0 + 3 == e1) ? p1 : ((e0 + 3 == e2) ? p2 : 0.f);
        *(float4*)(out + (size_t)(m0 + t) * NE + e0) = v;
    }
}

extern "C" void kernel_launch(void* const* d_in, const int* in_sizes, int n_in,
                              void* d_out, int out_size, void* d_ws, size_t ws_size,
                              hipStream_t stream) {
    const float* A     = (const float*)d_in[0];
    const float* noise = (const float*)d_in[1];
    const float* Wr    = (const float*)d_in[2];
    const float* br    = (const float*)d_in[3];
    const float* Wn    = (const float*)d_in[4];
    const float* bn    = (const float*)d_in[5];
    float* out = (float*)d_out;

    short* Bh = (short*)d_ws;
    short* Bl = Bh + W_ELEMS;

    prepack_w<<<dim3(W_ELEMS / 8 / 256), dim3(256), 0, stream>>>(Wr, Wn, Bh, Bl);
    router_mfma<<<dim3(T_TOKENS / M_TILE), dim3(256), 0, stream>>>(A, noise, br, bn, Bh, Bl, out);
}

// Round 8
// 234.161 us; speedup vs baseline: 1.0401x; 1.0401x over previous
//
#include <hip/hip_runtime.h>
#include <hip/hip_bf16.h>
#include <math.h>

// NoisyTopkRouter round 8: m97-style async A-staging.
// - A fp32 staged via __builtin_amdgcn_global_load_lds (width 16, 1 instr per
//   wave per chunk) into double-buffered LDS. No VGPR round-trip, no register
//   rotation -> no in-loop vmcnt chains; only the per-iteration barrier drain,
//   amortized across 4-6 independent blocks/CU.
// - XOR swizzle: lane fetches global 16B-chunk c=(lane&7)^(lane>>3) so the
//   fixed lane*16 LDS mapping yields conflict-free (2-way) frag reads.
// - Wave w: route ntile w + noise ntile w+4, all 32 rows (2 m-frags),
//   12 MFMAs/chunk, 4 B-loads/chunk (prepacked frag-order, L2-hot).

#define T_TOKENS 32768
#define D_MODEL  1024
#define NE       64
#define NCOL     128
#define M_TILE   32
#define NCHUNK   32
#define CS_LD    68
#define OUT_IDX_BASE ((size_t)T_TOKENS * NE)
#define W_ELEMS  (NCOL * D_MODEL)

typedef short  bf16x8  __attribute__((ext_vector_type(8)));
typedef float  floatx4 __attribute__((ext_vector_type(4)));

__device__ __forceinline__ float softplus_f(float x) {
    return fmaxf(x, 0.f) + log1pf(expf(-fabsf(x)));
}

__device__ __forceinline__ void gload_lds16(const float* g, void* l) {
    __builtin_amdgcn_global_load_lds(
        (const __attribute__((address_space(1))) void*)g,
        (__attribute__((address_space(3))) void*)l, 16, 0, 0);
}

// 8 floats -> bf16 hi/lo frag halves (RNE hi, exact residual, RNE lo) —
// numerics identical to rounds 2-7 (all passed).
__device__ __forceinline__ void cvt8frag(const float4 a, const float4 b,
                                         bf16x8* hi, bf16x8* lo) {
    float v[8] = {a.x, a.y, a.z, a.w, b.x, b.y, b.z, b.w};
    int hw[4], lw[4];
    #pragma unroll
    for (int p = 0; p < 4; ++p) {
        float2 f2 = make_float2(v[2 * p], v[2 * p + 1]);
        __hip_bfloat162 h2 = __float22bfloat162_rn(f2);
        int u; __builtin_memcpy(&u, &h2, 4);
        float h0 = __uint_as_float(((unsigned)u) << 16);
        float h1 = __uint_as_float(((unsigned)u) & 0xFFFF0000u);
        float2 l2 = make_float2(v[2 * p] - h0, v[2 * p + 1] - h1);
        __hip_bfloat162 L2 = __float22bfloat162_rn(l2);
        int ul; __builtin_memcpy(&ul, &L2, 4);
        hw[p] = u; lw[p] = ul;
    }
    int4 hp = make_int4(hw[0], hw[1], hw[2], hw[3]);
    int4 lp = make_int4(lw[0], lw[1], lw[2], lw[3]);
    __builtin_memcpy(hi, &hp, 16);
    __builtin_memcpy(lo, &lp, 16);
}

// ---------------- prepack: W -> hi/lo bf16 in B-frag order ----------------
// elem = ((ntile*128 + kgrp)*16 + n16)*8 + j ; value = W[ntile*16+n16][kgrp*8+j]
__global__ __launch_bounds__(256) void prepack_w(
    const float* __restrict__ Wr, const float* __restrict__ Wn,
    short* __restrict__ Bh, short* __restrict__ Bl)
{
    int g   = blockIdx.x * 256 + threadIdx.x;
    int n   = g & 15;
    int kg  = (g >> 4) & 127;
    int t2  = g >> 11;
    int col = t2 * 16 + n;
    const float* src = (col < NE ? Wr + (size_t)col * D_MODEL
                                 : Wn + (size_t)(col - NE) * D_MODEL) + kg * 8;
    float4 a = *(const float4*)src;
    float4 b = *(const float4*)(src + 4);
    bf16x8 hi, lo;
    cvt8frag(a, b, &hi, &lo);
    *(bf16x8*)(Bh + (size_t)g * 8) = hi;
    *(bf16x8*)(Bl + (size_t)g * 8) = lo;
}

// ---------------- main fused kernel ----------------
__global__ __launch_bounds__(256, 4) void router_mfma(
    const float* __restrict__ A,
    const float* __restrict__ noise,
    const float* __restrict__ br,
    const float* __restrict__ bn,
    const short* __restrict__ Bh,
    const short* __restrict__ Bl,
    float* __restrict__ out)
{
    // raw fp32 A chunk, double buffered: [buf][row*32 + slot*4 + j]
    // slot s holds global 16B-chunk c = s ^ (row&7)  (xor swizzle)
    __shared__ __align__(16) float Abuf[2][M_TILE * 32];
    __shared__ float Cs[M_TILE * CS_LD];
    __shared__ float s_p1[M_TILE], s_p2[M_TILE];
    __shared__ int   s_e1[M_TILE], s_e2[M_TILE];

    const int tid  = threadIdx.x;
    const int lane = tid & 63;
    const int wid  = tid >> 6;   // wave: route ntile wid, noise ntile wid+4
    const int n16  = lane & 15;
    const int quad = lane >> 4;
    const int m0   = blockIdx.x * M_TILE;

    // ---- staging addresses (wave w stages rows w*8 .. w*8+7) ----
    const int srow = (wid << 3) + (lane >> 3);          // 0..31
    const int schk = (lane & 7) ^ (lane >> 3);          // xor-swizzled chunk
    const float* gA = A + (size_t)(m0 + srow) * D_MODEL + schk * 4;
    float* lb0 = &Abuf[0][wid * 256];                   // wave-uniform LDS base
    float* lb1 = &Abuf[1][wid * 256];

    // ---- B frag bases ----
    const int bBaseR = ((wid * 128 + quad) * 16 + n16) * 8;
    const int bBaseN = (((wid + 4) * 128 + quad) * 16 + n16) * 8;

    // ---- frag-read LDS offsets (swizzled, conflict-free) ----
    int rdOff[2][2];   // [mf][half]
    #pragma unroll
    for (int mf = 0; mf < 2; ++mf) {
        int r  = mf * 16 + n16;
        int s0 = (2 * quad)     ^ (n16 & 7);
        int s1 = (2 * quad + 1) ^ (n16 & 7);
        rdOff[mf][0] = r * 32 + s0 * 4;
        rdOff[mf][1] = r * 32 + s1 * 4;
    }

    floatx4 accR[2], accN[2];
    #pragma unroll
    for (int mf = 0; mf < 2; ++mf) { accR[mf] = (floatx4)0.f; accN[mf] = (floatx4)0.f; }

    // ---- prologue: stage chunk 0 ----
    gload_lds16(gA, lb0);
    __syncthreads();

    for (int kc = 0; kc < NCHUNK; ++kc) {
        const int cur = kc & 1;

        // async-stage chunk kc+1 into the other buffer (no VGPR consumed)
        if (kc + 1 < NCHUNK)
            gload_lds16(gA + (kc + 1) * 32, (cur ? lb0 : lb1));

        // B for chunk kc (L2-hot prepacked planes)
        const int o = kc * 512;
        bf16x8 bhR = *(const bf16x8*)(Bh + bBaseR + o);
        bf16x8 blR = *(const bf16x8*)(Bl + bBaseR + o);
        bf16x8 bhN = *(const bf16x8*)(Bh + bBaseN + o);
        bf16x8 blN = *(const bf16x8*)(Bl + bBaseN + o);

        // A frags: fp32 from LDS (2-way banks = free), convert to hi/lo bf16
        bf16x8 ah[2], al[2];
        #pragma unroll
        for (int mf = 0; mf < 2; ++mf) {
            float4 f0 = *(const float4*)&Abuf[cur][rdOff[mf][0]];
            float4 f1 = *(const float4*)&Abuf[cur][rdOff[mf][1]];
            cvt8frag(f0, f1, &ah[mf], &al[mf]);
        }

        // 12 MFMAs
        #pragma unroll
        for (int mf = 0; mf < 2; ++mf) {
            accR[mf] = __builtin_amdgcn_mfma_f32_16x16x32_bf16(ah[mf], bhR, accR[mf], 0, 0, 0);
            accR[mf] = __builtin_amdgcn_mfma_f32_16x16x32_bf16(ah[mf], blR, accR[mf], 0, 0, 0);
            accR[mf] = __builtin_amdgcn_mfma_f32_16x16x32_bf16(al[mf], bhR, accR[mf], 0, 0, 0);
            accN[mf] = __builtin_amdgcn_mfma_f32_16x16x32_bf16(ah[mf], bhN, accN[mf], 0, 0, 0);
            accN[mf] = __builtin_amdgcn_mfma_f32_16x16x32_bf16(ah[mf], blN, accN[mf], 0, 0, 0);
            accN[mf] = __builtin_amdgcn_mfma_f32_16x16x32_bf16(al[mf], bhN, accN[mf], 0, 0, 0);
        }

        __syncthreads();   // drains staging(kc+1); buffers swap safely
    }

    // ---- lane-local fuse: noisy = route + noise * softplus(noise_logit) ----
    // D layout: col = lane&15, row = quad*4 + r
    {
        int e = wid * 16 + n16;
        float brv = br[e], bnv = bn[e];
        #pragma unroll
        for (int mf = 0; mf < 2; ++mf)
            #pragma unroll
            for (int rr = 0; rr < 4; ++rr) {
                int t = mf * 16 + quad * 4 + rr;
                float nz    = noise[(size_t)(m0 + t) * NE + e];
                float route = accR[mf][rr] + brv;
                float nl    = accN[mf][rr] + bnv;
                Cs[t * CS_LD + e] = fmaf(nz, softplus_f(nl), route);
            }
    }
    __syncthreads();

    // ---- top-2 + softmax (one thread per token; in-order scan = stable ties) ----
    if (tid < M_TILE) {
        const int t = tid;
        float v1 = -INFINITY, v2 = -INFINITY;
        int e1 = 0, e2 = 0;
        #pragma unroll
        for (int e4 = 0; e4 < 16; ++e4) {
            float4 q = *(const float4*)&Cs[t * CS_LD + e4 * 4];
            float qa[4] = {q.x, q.y, q.z, q.w};
            #pragma unroll
            for (int c = 0; c < 4; ++c) {
                float v = qa[c];
                int e = e4 * 4 + c;
                if (v > v1) { v2 = v1; e2 = e1; v1 = v; e1 = e; }
                else if (v > v2) { v2 = v; e2 = e; }
            }
        }
        float ex = expf(v2 - v1);
        float denom = 1.f + ex;
        s_p1[t] = 1.f / denom;
        s_p2[t] = ex / denom;
        s_e1[t] = e1;
        s_e2[t] = e2;
        float2 iv = make_float2((float)e1, (float)e2);
        *(float2*)(out + OUT_IDX_BASE + (size_t)(m0 + t) * 2) = iv;
    }
    __syncthreads();

    // ---- coalesced scatter of router_output [32 tokens x 64 experts] ----
    #pragma unroll
    for (int i = 0; i < 2; ++i) {
        int gi = i * 256 + tid;       // 0..511 float4s
        int t  = gi >> 4;
        int e0 = (gi & 15) * 4;
        float p1 = s_p1[t], p2 = s_p2[t];
        int   e1 = s_e1[t], e2 = s_e2[t];
        float4 v;
        v.x = (e0 + 0 == e1) ? p1 : ((e0 + 0 == e2) ? p2 : 0.f);
        v.y = (e0 + 1 == e1) ? p1 : ((e0 + 1 == e2) ? p2 : 0.f);
        v.z = (e0 + 2 == e1) ? p1 : ((e0 + 2 == e2) ? p2 : 0.f);
        v.w = (e0 + 3 == e1) ? p1 : ((e0 + 3 == e2) ? p2 : 0.f);
        *(float4*)(out + (size_t)(m0 + t) * NE + e0) = v;
    }
}

extern "C" void kernel_launch(void* const* d_in, const int* in_sizes, int n_in,
                              void* d_out, int out_size, void* d_ws, size_t ws_size,
                              hipStream_t stream) {
    const float* A     = (const float*)d_in[0];
    const float* noise = (const float*)d_in[1];
    const float* Wr    = (const float*)d_in[2];
    const float* br    = (const float*)d_in[3];
    const float* Wn    = (const float*)d_in[4];
    const float* bn    = (const float*)d_in[5];
    float* out = (float*)d_out;

    short* Bh = (short*)d_ws;
    short* Bl = Bh + W_ELEMS;

    prepack_w<<<dim3(W_ELEMS / 8 / 256), dim3(256), 0, stream>>>(Wr, Wn, Bh, Bl);
    router_mfma<<<dim3(T_TOKENS / M_TILE), dim3(256), 0, stream>>>(A, noise, br, bn, Bh, Bl, out);
}